// Round 10
// baseline (589.743 us; speedup 1.0000x reference)
//
#include <hip/hip_runtime.h>

// ---------------------------------------------------------------------------
// BiLSTM + MLP head, MI355X (gfx950).
//   B=32, T=512, D=2048, H=128, G=4H=512, M=B*T=16384.
//   reference's hs_b[:, -1] = ONE backward step from zero state (reverse scan
//   emits carry-after-first-step at index T-1) -> backward LSTM is 1 step.
// Dispatches:
//   1) cvt_w:     W_ih_f fp32 -> f16 (RNE)
//   2) bwd_gates: partial dots for the single backward step (split-K x 8)
//   3) gemm_xp:   xp = x @ W_ih_f^T + (b_ih_f + b_hh_f), f16 MFMA, fp32 out
//   4) scan:      forward LSTM recurrence, 32 blocks x 512 thr (2 waves/SIMD),
//                 4-way k-split fdot2 with gate-slot permutation, DPP
//                 butterfly reduce, ONE activation per lane, replicated c,
//                 1 barrier/step, xp prefetched 2 steps ahead
//   5) head:      bwd-gate reduce+activations, fc1->fc2->fc3->softmax
// Workspace: 36,192,256 bytes.
// ---------------------------------------------------------------------------

typedef unsigned int   u32;
typedef unsigned short u16;
typedef float f4  __attribute__((ext_vector_type(4)));
typedef u32   u4  __attribute__((ext_vector_type(4)));
typedef _Float16 h2v __attribute__((ext_vector_type(2)));

#if defined(__has_builtin)
#  if __has_builtin(__builtin_amdgcn_fdot2)
#    define HAVE_FDOT2 1
#  endif
#  if __has_builtin(__builtin_amdgcn_mov_dpp)
#    define HAVE_MOVDPP 1
#  endif
#  if __has_builtin(__builtin_amdgcn_rcpf)
#    define HAVE_RCPF 1
#  endif
#endif

// MFMA via inline asm. acc: float4 (C/D), a,b: 8 f16 as uint4.
#define MFMA_F16(acc, a, b) \
  asm("v_mfma_f32_16x16x32_f16 %0, %1, %2, %0" : "+v"(acc) : "v"(a), "v"(b))

__device__ __forceinline__ float sigf(float x) { return 1.0f / (1.0f + __expf(-x)); }
__device__ __forceinline__ float tanh_fast(float x) {
  float e = __expf(2.0f * x);           // inf for large x -> 1; 0 -> -1
  return 1.0f - 2.0f / (e + 1.0f);
}
// fast reciprocal (v_rcp_f32, ~1 ulp) with portable fallback
__device__ __forceinline__ float rcpf(float x) {
#if HAVE_RCPF
  return __builtin_amdgcn_rcpf(x);
#else
  return 1.0f / x;
#endif
}
// 2x f32 -> packed f16 (RTZ), one instruction
__device__ __forceinline__ u32 pkrtz(float a, float b) {
  u32 r;
  asm("v_cvt_pkrtz_f16_f32 %0, %1, %2" : "=v"(r) : "v"(a), "v"(b));
  return r;
}
__device__ __forceinline__ u16 f16_rne(float x) {
  union { _Float16 f; u16 s; } v; v.f = (_Float16)x; return v.s;
}
// dot of two f16x2 words + f32 acc (v_dot2_f32_f16 when available)
__device__ __forceinline__ float fdot2u(u32 a, u32 b, float c) {
  union { u32 u; h2v h; } ua, ub;
  ua.u = a; ub.u = b;
#if HAVE_FDOT2
  return __builtin_amdgcn_fdot2(ua.h, ub.h, c, false);
#else
  return c + (float)ua.h[0] * (float)ub.h[0] + (float)ua.h[1] * (float)ub.h[1];
#endif
}
__device__ __forceinline__ u32 pack_h2(float a, float b) {
  union { h2v h; u32 u; } v;
  v.h[0] = (_Float16)a; v.h[1] = (_Float16)b;
  return v.u;
}
// lane^1 / lane^2 exchange via DPP quad_perm (VALU pipe, no LDS traffic)
__device__ __forceinline__ float dpp_x1(float x) {
#if HAVE_MOVDPP
  union { float f; int i; } v; v.f = x;
  v.i = __builtin_amdgcn_mov_dpp(v.i, 0xB1, 0xF, 0xF, true);  // [1,0,3,2]
  return v.f;
#else
  return __shfl_xor(x, 1);
#endif
}
__device__ __forceinline__ float dpp_x2(float x) {
#if HAVE_MOVDPP
  union { float f; int i; } v; v.f = x;
  v.i = __builtin_amdgcn_mov_dpp(v.i, 0x4E, 0xF, 0xF, true);  // [2,3,0,1]
  return v.f;
#else
  return __shfl_xor(x, 2);
#endif
}

// ---------------------------------------------------------------------------
// W_ih_f fp32 -> f16 (RNE)
// ---------------------------------------------------------------------------
__global__ void cvt_w_kernel(const float* __restrict__ in, u16* __restrict__ out, int n8) {
  int i = blockIdx.x * blockDim.x + threadIdx.x;
  int stride = gridDim.x * blockDim.x;
  for (; i < n8; i += stride) {
    f4 v0 = *(const f4*)(in + (size_t)i * 8);
    f4 v1 = *(const f4*)(in + (size_t)i * 8 + 4);
    union { u16 s[8]; u4 v; } o;
    o.s[0] = f16_rne(v0.x); o.s[1] = f16_rne(v0.y);
    o.s[2] = f16_rne(v0.z); o.s[3] = f16_rne(v0.w);
    o.s[4] = f16_rne(v1.x); o.s[5] = f16_rne(v1.y);
    o.s[6] = f16_rne(v1.z); o.s[7] = f16_rne(v1.w);
    *(u4*)(out + (size_t)i * 8) = o.v;
  }
}

// ---------------------------------------------------------------------------
// Backward step partial dots: gb[s][b][g] = dot(Wib[g, s*256:+256], x[b,511,s*256:+256])
// 256 blocks = 32 batches x 8 K-slices; per-CU W traffic 0.5 MB.
// ---------------------------------------------------------------------------
__global__ __launch_bounds__(512) void bwd_gates_kernel(
    const float* __restrict__ x,      // [32, 512, 2048]
    const float* __restrict__ Wib,    // [512, 2048]
    float* __restrict__ gb)           // [8, 32, 512]
{
  const int blk = blockIdx.x;
  const int b = blk >> 3, s = blk & 7;
  const int g = threadIdx.x;
  __shared__ alignas(16) float xr[256];
  const float* xrow = x + ((size_t)b * 512 + 511) * 2048 + s * 256;
  if (g < 64) *(f4*)(xr + g * 4) = *(const f4*)(xrow + g * 4);
  __syncthreads();

  const float* wrow = Wib + (size_t)g * 2048 + s * 256;
  float a0 = 0.0f, a1 = 0.0f;
  #pragma unroll 8
  for (int i = 0; i < 64; i += 2) {
    f4 w0 = *(const f4*)(wrow + i * 4);
    f4 h0 = *(const f4*)(xr + i * 4);
    f4 w1 = *(const f4*)(wrow + i * 4 + 4);
    f4 h1 = *(const f4*)(xr + i * 4 + 4);
    a0 += w0.x * h0.x + w0.y * h0.y + w0.z * h0.z + w0.w * h0.w;
    a1 += w1.x * h1.x + w1.y * h1.y + w1.z * h1.z + w1.w * h1.w;
  }
  gb[((size_t)s * 32 + b) * 512 + g] = a0 + a1;
}

// ---------------------------------------------------------------------------
// xp[m, n] = sum_k x[m,k] * W_ih_f[n,k] + (b_ih_f[n] + b_hh_f[n])
// M=16384, K=2048, N=512. Tile 128x128, BK=64, 256 thr (4 waves, 2x2 of 64x64).
// A converted fp32->f16 (RTZ) in-register during staging; LDS 16B-chunk XOR
// swizzle so ds_write_b128 / ds_read_b128 are conflict-free per 16-lane phase.
// ---------------------------------------------------------------------------
__global__ __launch_bounds__(256) void gemm_xp_kernel(
    const float* __restrict__ A,    // [16384, 2048] fp32
    const u16*  __restrict__ Bw,    // [512, 2048] f16
    const float* __restrict__ bih,
    const float* __restrict__ bhh,
    float* __restrict__ C)          // [16384, 512] fp32
{
  constexpr int K = 2048, N = 512;
  __shared__ alignas(16) u16 As[128 * 64];
  __shared__ alignas(16) u16 Bs[128 * 64];

  const int tid  = threadIdx.x;
  const int lane = tid & 63;
  const int w    = tid >> 6;
  const int wr   = w >> 1, wc = w & 1;

  // XCD-aware swizzle: 512 blocks, 8 XCDs -> the 4 n-tiles sharing an A-panel
  // are consecutively dispatched on the same XCD (L2 reuse of fp32 A panel).
  int bid = blockIdx.x;
  int wg  = (bid & 7) * 64 + (bid >> 3);
  const int mt = wg >> 2, nt = wg & 3;
  const int m0 = mt * 128, n0 = nt * 128;

  // staging: 1024 16B-chunks per tile; thread covers chunks i*256+tid, i=0..3
  const int rbase = tid >> 3;             // row 0..31 (+i*32)
  const int cbase = tid & 7;              // chunk-in-row 0..7
  const float* aG = A  + (size_t)(m0 + rbase) * K + cbase * 8;
  const u16*   bG = Bw + (size_t)(n0 + rbase) * K + cbase * 8;
  const int wbyte = rbase * 128 + ((cbase ^ (rbase & 7)) << 4); // + i*4096

  // fragment read bases
  const int l15 = lane & 15, hi = lane >> 4, sx = lane & 7;
  const int arow = (wr * 64 + l15) * 128;   // + mi*2048 bytes
  const int brow = (wc * 64 + l15) * 128;   // + ni*2048 bytes

  f4 acc[4][4] = {};

  u4 ra[4], rb[4];
  auto loadA = [&](int kt, u4* r) {
    const float* ag = aG + kt * 64;
    #pragma unroll
    for (int i = 0; i < 4; ++i) {
      f4 v0 = *(const f4*)(ag + (size_t)(i * 32) * K);
      f4 v1 = *(const f4*)(ag + (size_t)(i * 32) * K + 4);
      u4 t;
      t.x = pkrtz(v0.x, v0.y);
      t.y = pkrtz(v0.z, v0.w);
      t.z = pkrtz(v1.x, v1.y);
      t.w = pkrtz(v1.z, v1.w);
      r[i] = t;
    }
  };
  auto loadB = [&](int kt, u4* r) {
    const u16* bg = bG + kt * 64;
    #pragma unroll
    for (int i = 0; i < 4; ++i)
      r[i] = *(const u4*)(bg + (size_t)(i * 32) * K);
  };

  loadA(0, ra); loadB(0, rb);

  for (int kt = 0; kt < 32; ++kt) {
    __syncthreads();                       // previous compute done, LDS free
    #pragma unroll
    for (int i = 0; i < 4; ++i) {
      *(u4*)((char*)As + i * 4096 + wbyte) = ra[i];
      *(u4*)((char*)Bs + i * 4096 + wbyte) = rb[i];
    }
    __syncthreads();
    if (kt + 1 < 32) { loadA(kt + 1, ra); loadB(kt + 1, rb); }  // overlap w/ MFMA
    #pragma unroll
    for (int ks = 0; ks < 2; ++ks) {
      const int co = ((ks * 4 + hi) ^ sx) << 4;
      u4 af[4], bf[4];
      #pragma unroll
      for (int mi = 0; mi < 4; ++mi)
        af[mi] = *(const u4*)((const char*)As + arow + mi * 2048 + co);
      #pragma unroll
      for (int ni = 0; ni < 4; ++ni)
        bf[ni] = *(const u4*)((const char*)Bs + brow + ni * 2048 + co);
      #pragma unroll
      for (int mi = 0; mi < 4; ++mi)
        #pragma unroll
        for (int ni = 0; ni < 4; ++ni)
          MFMA_F16(acc[mi][ni], af[mi], bf[ni]);
    }
  }

  asm volatile("s_nop 7\ns_nop 7\ns_nop 7" :::);  // MFMA->VALU hazard insurance

  float biasv[4];
  #pragma unroll
  for (int ni = 0; ni < 4; ++ni) {
    int n = n0 + wc * 64 + ni * 16 + l15;
    biasv[ni] = bih[n] + bhh[n];
  }
  #pragma unroll
  for (int mi = 0; mi < 4; ++mi) {
    int mb = m0 + wr * 64 + mi * 16 + hi * 4;
    #pragma unroll
    for (int ni = 0; ni < 4; ++ni) {
      int n = n0 + wc * 64 + ni * 16 + l15;
      #pragma unroll
      for (int r = 0; r < 4; ++r)
        C[(size_t)(mb + r) * N + n] = acc[mi][ni][r] + biasv[ni];
    }
  }
}

// ---------------------------------------------------------------------------
// Forward LSTM scan: 32 blocks (1/batch) x 512 threads (8 waves = 2/SIMD).
// Thread t: h-unit u = t>>2, k-quarter kp = t&3 (32 of 128 h elements).
// GATE-SLOT PERMUTATION: lane kp's slot m accumulates gate (kp^m) over its
// k-quarter (64 fdot2). A 2-round DPP butterfly (a[m] += dpp_x1(a[m^1]);
// a[m] += dpp_x2(a[m^2])) leaves slot m = FULL sum of gate kp^m.
// Each lane then activates ONLY its own gate (slot 0) with the branchless
// unified formula act(x) = 1 - a*rcp(exp(a*x)+1), a=1 (sigmoid, gates i/f/o)
// or a=2 (tanh, gate g). 3 DPP gathers + 8 cndmask canonicalize to
// (i,f,g,o); the c-state update is replicated per k-group (no serial tail).
// Each thread loads only ITS gate's xp, PREFETCHED 2 STEPS AHEAD (covers
// L3/HBM latency ~900 cyc at ~450 cyc/step).
// h kept as f16x2 in double-buffered LDS -> ONE barrier per step.
// Verified lane-trace: for kp in {0,1,2,3}, (ai,af,ag,ao) = gates (0,1,2,3).
// ---------------------------------------------------------------------------
__global__ __launch_bounds__(512, 2) void lstm_scan_kernel(
    const float* __restrict__ xp,     // [16384, 512], biases included
    const float* __restrict__ Whh,    // [512, 128] fp32
    float* __restrict__ hf_out)       // [32, 128]
{
  const int b = blockIdx.x, t = threadIdx.x;
  const int u = t >> 2, kp = t & 3, k0 = kp * 32;   // 32 f16 elems = 16 words
  __shared__ alignas(16) u32 h2[2][64];   // f16x2 packed h, double buffer

  // slot m <- W_hh row of gate (kp^m) for unit u, cols [k0, k0+32) as f16
  u32 w2[4][16];
  #pragma unroll
  for (int m = 0; m < 4; ++m) {
    const float* wr = Whh + (size_t)((kp ^ m) * 128 + u) * 128 + k0;
    #pragma unroll
    for (int j = 0; j < 8; ++j) {
      f4 v = *(const f4*)(wr + j * 4);
      w2[m][j * 2 + 0] = pack_h2(v.x, v.y);
      w2[m][j * 2 + 1] = pack_h2(v.z, v.w);
    }
  }
  if (t < 64) h2[0][t] = 0u;              // step-0 read buffer = zeros
  float c = 0.0f, hh = 0.0f;

  const bool m1 = (kp & 1) != 0, m2 = (kp & 2) != 0;
  const float aa = (kp == 2) ? 2.0f : 1.0f;   // own gate: g -> tanh, else sig

  const float* xb = xp + (size_t)b * 512 * 512 + kp * 128 + u;  // own gate col
  float xq  = xb[0];                       // step 0
  float xn1 = xb[512];                     // step 1
  __syncthreads();

  for (int s = 0; s < 512; ++s) {
    const int rbuf = s & 1, wbuf = rbuf ^ 1;
    // this thread's k-quarter of h: 4 x b128 (16-way same-address broadcast,
    // 2-way bank alias -> conflict-free)
    u4 hv[4];
    const u32* hp = &h2[rbuf][kp * 16];
    #pragma unroll
    for (int j = 0; j < 4; ++j) hv[j] = *(const u4*)(hp + j * 4);
    // prefetch xp TWO steps ahead (consumed ~2 steps later -> latency covered)
    float xn2 = xb[(size_t)(s + 2 < 512 ? s + 2 : 511) * 512];

    float a0 = 0.0f, a1 = 0.0f, a2 = 0.0f, a3 = 0.0f;   // slots 0..3
    #pragma unroll
    for (int j = 0; j < 4; ++j) {
      #pragma unroll
      for (int m = 0; m < 4; ++m) {
        const u32 hw = hv[j][m];
        a0 = fdot2u(w2[0][4 * j + m], hw, a0);
        a1 = fdot2u(w2[1][4 * j + m], hw, a1);
        a2 = fdot2u(w2[2][4 * j + m], hw, a2);
        a3 = fdot2u(w2[3][4 * j + m], hw, a3);
      }
    }
    // butterfly round 1 (partner ^1): slot m absorbs partner's slot m^1
    {
      float t0 = dpp_x1(a1), t1 = dpp_x1(a0), t2 = dpp_x1(a3), t3 = dpp_x1(a2);
      a0 += t0; a1 += t1; a2 += t2; a3 += t3;
    }
    // butterfly round 2 (partner ^2): slot m absorbs partner's slot m^2
    {
      float t0 = dpp_x2(a2), t1 = dpp_x2(a3), t2 = dpp_x2(a0), t3 = dpp_x2(a1);
      a0 += t0; a1 += t1; a2 += t2; a3 += t3;
    }
    // a0 = full pre-activation of OWN gate (kp); activate branchlessly:
    // sig(x) = 1 - 1/(e^x+1);  tanh(x) = 1 - 2/(e^{2x}+1)  ->  a in {1,2}
    float e  = __expf(aa * (a0 + xq));
    float b0 = 1.0f - aa * rcpf(e + 1.0f);
    // gather the other 3 gates' activations (lane kp^d holds gate kp^d)
    float b1 = dpp_x1(b0);          // act(gate kp^1)
    float b2 = dpp_x2(b0);          // act(gate kp^2)
    float b3 = dpp_x2(b1);          // act(gate kp^3)
    // canonicalize to (i,f,g,o): gate gidx lives in reg b_{gidx^kp}
    float p  = m1 ? b1 : b0, pp = m1 ? b0 : b1;
    float r  = m1 ? b3 : b2, rr = m1 ? b2 : b3;
    float ai = m2 ? r  : p;
    float af = m2 ? rr : pp;
    float ag = m2 ? p  : r;
    float ao = m2 ? pp : rr;
    c  = af * c + ai * ag;                 // replicated per k-group
    hh = ao * tanh_fast(c);
    if (kp == 0) ((u16*)h2)[wbuf * 128 + u] = f16_rne(hh);
    xq = xn1; xn1 = xn2;
    __syncthreads();                       // write visible; rbuf reusable
  }
  if (kp == 0) hf_out[b * 128 + u] = hh;
}

// ---------------------------------------------------------------------------
// head: reduce bwd partials -> h_b; last = [h_f, h_b];
//       x3 = ((last@W1^T+b1)@W2^T+b2)@W3^T+b3; softmax
// ---------------------------------------------------------------------------
__global__ __launch_bounds__(256) void head_kernel(
    const float* __restrict__ hf,     // [32,128]
    const float* __restrict__ gb,     // [8,32,512] bwd partial dots
    const float* __restrict__ bib, const float* __restrict__ bhb,
    const float* __restrict__ W1, const float* __restrict__ b1,
    const float* __restrict__ W2, const float* __restrict__ b2,
    const float* __restrict__ W3, const float* __restrict__ b3,
    float* __restrict__ out)          // [32, 11]
{
  const int b = blockIdx.x, i = threadIdx.x;
  __shared__ alignas(16) float last[256];
  __shared__ alignas(16) float x1[256];
  __shared__ alignas(16) float x2[64];
  __shared__ float x3[11];
  if (i < 128) {
    last[i] = hf[b * 128 + i];
  } else {
    const int h = i - 128;
    float gi = bib[h] + bhb[h];
    float gg = bib[256 + h] + bhb[256 + h];
    float go = bib[384 + h] + bhb[384 + h];
    #pragma unroll
    for (int s = 0; s < 8; ++s) {
      const float* gbp = gb + ((size_t)s * 32 + b) * 512;
      gi += gbp[h]; gg += gbp[256 + h]; go += gbp[384 + h];
    }
    float cc = sigf(gi) * tanh_fast(gg);
    last[i] = sigf(go) * tanh_fast(cc);
  }
  __syncthreads();

  {
    float a = b1[i];
    const float* w = W1 + (size_t)i * 256;
    #pragma unroll 8
    for (int k = 0; k < 64; ++k) {
      f4 wv = *(const f4*)(w + k * 4);
      f4 lv = *(const f4*)(last + k * 4);
      a += wv.x * lv.x + wv.y * lv.y + wv.z * lv.z + wv.w * lv.w;
    }
    x1[i] = a;
  }
  __syncthreads();
  if (i < 64) {
    float a = b2[i];
    const float* w = W2 + (size_t)i * 256;
    #pragma unroll 8
    for (int k = 0; k < 64; ++k) {
      f4 wv = *(const f4*)(w + k * 4);
      f4 lv = *(const f4*)(x1 + k * 4);
      a += wv.x * lv.x + wv.y * lv.y + wv.z * lv.z + wv.w * lv.w;
    }
    x2[i] = a;
  }
  __syncthreads();
  if (i < 11) {
    float a = b3[i];
    const float* w = W3 + (size_t)i * 64;
    #pragma unroll
    for (int k = 0; k < 16; ++k) {
      f4 wv = *(const f4*)(w + k * 4);
      f4 lv = *(const f4*)(x2 + k * 4);
      a += wv.x * lv.x + wv.y * lv.y + wv.z * lv.z + wv.w * lv.w;
    }
    x3[i] = a;
  }
  __syncthreads();
  if (i < 11) {
    float m = x3[0];
    #pragma unroll
    for (int j = 1; j < 11; ++j) m = fmaxf(m, x3[j]);
    float s = 0.0f;
    #pragma unroll
    for (int j = 0; j < 11; ++j) s += __expf(x3[j] - m);
    out[b * 11 + i] = __expf(x3[i] - m) / s;
  }
}

// ---------------------------------------------------------------------------
extern "C" void kernel_launch(void* const* d_in, const int* in_sizes, int n_in,
                              void* d_out, int out_size, void* d_ws, size_t ws_size,
                              hipStream_t stream)
{
  const float* inputs = (const float*)d_in[0];
  const float* W_ih_f = (const float*)d_in[1];
  const float* W_hh_f = (const float*)d_in[2];
  const float* b_ih_f = (const float*)d_in[3];
  const float* b_hh_f = (const float*)d_in[4];
  const float* W_ih_b = (const float*)d_in[5];
  const float* W_hh_b = (const float*)d_in[6];  (void)W_hh_b;  // unused: 1-step bwd, h0=0
  const float* b_ih_b = (const float*)d_in[7];
  const float* b_hh_b = (const float*)d_in[8];
  const float* W1 = (const float*)d_in[9];
  const float* b1 = (const float*)d_in[10];
  const float* W2 = (const float*)d_in[11];
  const float* b2 = (const float*)d_in[12];
  const float* W3 = (const float*)d_in[13];
  const float* b3 = (const float*)d_in[14];
  float* out = (float*)d_out;

  char* ws = (char*)d_ws;
  u16*   WF16 = (u16*)(ws);                        // 2,097,152 B
  float* XP   = (float*)(ws + 2097152);            // 33,554,432 B
  float* HF   = (float*)(ws + 35651584);           // 16,384 B
  float* GB   = (float*)(ws + 35667968);           // 524,288 B  [8,32,512]
  if (ws_size < 36192256) return;

  cvt_w_kernel<<<512, 256, 0, stream>>>(W_ih_f, WF16, 131072);
  bwd_gates_kernel<<<256, 512, 0, stream>>>(inputs, W_ih_b, GB);
  gemm_xp_kernel<<<512, 256, 0, stream>>>(inputs, WF16, b_ih_f, b_hh_f, XP);
  lstm_scan_kernel<<<32, 512, 0, stream>>>(XP, W_hh_f, HF);
  head_kernel<<<32, 256, 0, stream>>>(HF, GB, b_ih_b, b_hh_b,
                                      W1, b1, W2, b2, W3, b3, out);
}